// Round 1
// baseline (18.871 us; speedup 1.0000x reference)
//
#include <hip/hip_runtime.h>
#include <math.h>

#define CELLS 7
#define NCH   30      // 20 classes + 2 conf + 2*4 box
#define NCLS  20
#define NPRED 1470    // 7*7*30

// One 64-thread block per image.
__global__ __launch_bounds__(64) void yolo_loss_kernel(
    const float* __restrict__ predicts,   // [B,7,7,30]
    const float* __restrict__ labels,     // [B,20,5]
    const int*   __restrict__ objects_num,// [B]
    float*       __restrict__ partial)    // [B]
{
    const int b   = blockIdx.x;
    const int tid = threadIdx.x;

    __shared__ __align__(16) float sP[NPRED];
    __shared__ float S2[49];

    // ---- stage predicts[b] into LDS (float2-coalesced; 5880 B is 8B-aligned) ----
    {
        const float2* src = (const float2*)(predicts + (size_t)b * NPRED);
        float2* dst = (float2*)sP;
        #pragma unroll
        for (int i = tid; i < NPRED / 2; i += 64) dst[i] = src[i];
    }
    __syncthreads();

    // ---- per-cell class-square sums + total conf-square (per image) ----
    float c2 = 0.f;
    if (tid < 49) {
        const float* cp = sP + tid * NCH;
        float s = 0.f;
        #pragma unroll
        for (int c = 0; c < NCLS; ++c) s += cp[c] * cp[c];
        S2[tid] = s;
        c2 = cp[20] * cp[20] + cp[21] * cp[21];
    }
    #pragma unroll
    for (int off = 32; off; off >>= 1) c2 += __shfl_xor(c2, off, 64);
    // all lanes now hold sum over all 98 p_C^2
    __syncthreads();

    const int nobj = objects_num[b];
    float loss = 0.f;

    if (tid < 20 && tid < nobj) {
        const float GS = 64.f, IMG = 448.f;
        const float* lb = labels + (size_t)b * 100 + tid * 5;
        const float x = lb[0], y = lb[1], w = lb[2], h = lb[3];
        const int cls = (int)lb[4];

        const int cx = (int)floorf(x / GS);
        const int cy = (int)floorf(y / GS);
        const float* cell = sP + (cy * 7 + cx) * NCH;

        // truth corners
        const float tx0 = x - w * 0.5f, ty0 = y - h * 0.5f;
        const float tx1 = x + w * 0.5f, ty1 = y + h * 0.5f;
        const float sq2 = (tx1 - tx0) * (ty1 - ty0);

        float iou[2], pc[2], px[2], py[2], pw[2], ph[2];
        #pragma unroll
        for (int p = 0; p < 2; ++p) {
            const float* bp = cell + NCLS + 2 + 4 * p;   // channels 22..29
            const float bx = bp[0] * GS + GS * (float)cx;
            const float by = bp[1] * GS + GS * (float)cy;
            const float bw = bp[2] * IMG;
            const float bh = bp[3] * IMG;
            px[p] = bx; py[p] = by; pw[p] = bw; ph[p] = bh;
            const float ax0 = bx - bw * 0.5f, ay0 = by - bh * 0.5f;
            const float ax1 = bx + bw * 0.5f, ay1 = by + bh * 0.5f;
            const float lux = fmaxf(ax0, tx0), luy = fmaxf(ay0, ty0);
            const float rdx = fminf(ax1, tx1), rdy = fminf(ay1, ty1);
            const float iw = fmaxf(rdx - lux, 0.f), ih = fmaxf(rdy - luy, 0.f);
            const float ia = iw * ih;
            const float sq1 = (ax1 - ax0) * (ay1 - ay0);
            iou[p] = ia / (sq1 + sq2 - ia + 1e-6f);
            pc[p]  = cell[NCLS + p];
        }

        const float miou = fmaxf(iou[0], iou[1]);
        const float sqw = sqrtf(fabsf(w)), sqh = sqrtf(fabsf(h));

        float obj = 0.f, coord = 0.f, isumc2 = 0.f;
        #pragma unroll
        for (int p = 0; p < 2; ++p) {
            if (iou[p] >= miou) {          // ties -> both, matches reference >=
                const float d = pc[p] - iou[p];
                obj    += d * d;
                isumc2 += pc[p] * pc[p];
                const float dx = (px[p] - x) / GS;
                const float dy = (py[p] - y) / GS;
                const float psw = sqrtf(fminf(fmaxf(pw[p], 0.f), IMG));
                const float psh = sqrtf(fminf(fmaxf(ph[p], 0.f), IMG));
                const float dw = psw - sqw, dh = psh - sqh;
                coord += dx * dx + dy * dy + (dw * dw + dh * dh) / IMG;
            }
        }

        const float object_loss   = 0.5f  * obj;            // OBJECT_SCALE=1, _l2
        const float noobject_loss = 0.25f * (c2 - isumc2);   // 0.5 * 0.5
        const float coord_loss    = 2.5f  * coord;           // 5 * 0.5

        // class loss over object_mask rectangle; CLASS_SCALE * 0.5 = 1
        const int x0 = (int)fmaxf(0.f, floorf(tx0 / GS));
        const int x1 = (int)fminf(7.f, ceilf (tx1 / GS));
        const int y0 = (int)fmaxf(0.f, floorf(ty0 / GS));
        const int y1 = (int)fminf(7.f, ceilf (ty1 / GS));
        float cl = 0.f;
        for (int iy = y0; iy < y1; ++iy)
            for (int ix = x0; ix < x1; ++ix) {
                const int ci = iy * 7 + ix;
                cl += S2[ci] - 2.f * sP[ci * NCH + cls] + 1.f;
            }

        loss = object_loss + noobject_loss + coord_loss + cl;
    }

    // wave-reduce 64 lanes (deterministic tree)
    #pragma unroll
    for (int off = 32; off; off >>= 1) loss += __shfl_xor(loss, off, 64);
    if (tid == 0) partial[b] = loss;
}

// Deterministic final reduction of B partials, / B.
__global__ __launch_bounds__(256) void yolo_reduce_kernel(
    const float* __restrict__ partial, float* __restrict__ out, int n)
{
    const int tid = threadIdx.x;
    double s = 0.0;
    for (int i = tid; i < n; i += 256) s += (double)partial[i];
    #pragma unroll
    for (int off = 32; off; off >>= 1) s += __shfl_xor(s, off, 64);
    __shared__ double sd[4];
    if ((tid & 63) == 0) sd[tid >> 6] = s;
    __syncthreads();
    if (tid == 0) {
        const double t = sd[0] + sd[1] + sd[2] + sd[3];
        out[0] = (float)(t / (double)n);
    }
}

extern "C" void kernel_launch(void* const* d_in, const int* in_sizes, int n_in,
                              void* d_out, int out_size, void* d_ws, size_t ws_size,
                              hipStream_t stream) {
    const float* predicts = (const float*)d_in[0];
    const float* labels   = (const float*)d_in[1];
    const int*   objnum   = (const int*)d_in[2];
    const int B = in_sizes[0] / NPRED;   // 4096

    float* partials = (float*)d_ws;      // B floats = 16 KB scratch

    yolo_loss_kernel<<<B, 64, 0, stream>>>(predicts, labels, objnum, partials);
    yolo_reduce_kernel<<<1, 256, 0, stream>>>(partials, (float*)d_out, B);
}